// Round 4
// baseline (344.362 us; speedup 1.0000x reference)
//
#include <hip/hip_runtime.h>

#define BATCH 32
#define SEQ 4096
#define DMODEL 256
#define NCLS 5

typedef float v2f __attribute__((ext_vector_type(2)));

// packed fp32 FMA (VOP3P): D[i] = A[i]*B[i] + C[i], i=0,1
__device__ __forceinline__ v2f pk_fma(v2f a, v2f b, v2f c) {
    v2f d;
    asm("v_pk_fma_f32 %0, %1, %2, %3" : "=v"(d) : "v"(a), "v"(b), "v"(c));
    return d;
}

// wave-private LDS RAW fence: drain DS queue + stop compiler reordering.
// (No s_barrier: each wave reads only what it wrote itself.)
#define LDS_FENCE() asm volatile("s_waitcnt lgkmcnt(0)" ::: "memory")

// Wave covers 2 channels (d = 2*pr + dd) of batch b. Lane: dd=l>>5, c=l&31;
// lane owns modes c and c+32 of channel d (folded s' = A s' + P x + Q).
// Chunk of 32 t: write partials (s_c+s_{c+32}) to LDS row j (stride 36,
// write banks (4j+c)%32 across c: conflict-free; read row c as 8x b128),
// lane c reduces timestep t0+j0+c, gelu, pool accumulate.
__global__ __launch_bounds__(256) void ssm_scan_kernel(
    const float* __restrict__ x,      // [B, T]
    const float* __restrict__ w_in,   // [D]
    const float* __restrict__ b_in,   // [D]
    const float* __restrict__ A_diag, // [D, 64]
    const float* __restrict__ B_in,   // [D, 64]
    const float* __restrict__ C_out,  // [D, 64]
    const float* __restrict__ D_skip, // [D]
    float* __restrict__ pooled)       // [B, 2D]
{
    __shared__ float tile[4][2304];   // per wave: 2 ch * 32 rows * 36

    const int wid  = threadIdx.x >> 6;
    const int lane = threadIdx.x & 63;
    const int gw   = blockIdx.x * 4 + wid;   // 0..4095
    const int b    = gw >> 7;                // 0..31
    const int pr   = gw & 127;               // channel pair
    const int dd   = lane >> 5;
    const int c    = lane & 31;
    const int d    = 2 * pr + dd;

    const float A0  = A_diag[d * 64 + c];
    const float A1  = A_diag[d * 64 + c + 32];
    const float wd  = w_in[d];
    const float bd  = b_in[d];
    const float CB0 = B_in[d * 64 + c]      * C_out[d * 64 + c];
    const float CB1 = B_in[d * 64 + c + 32] * C_out[d * 64 + c + 32];
    const v2f A2 = {A0, A1};
    const v2f P2 = {CB0 * wd, CB1 * wd};
    const v2f Q2 = {CB0 * bd, CB1 * bd};
    const float Dw = D_skip[d] * wd;
    const float Db = D_skip[d] * bd;

    v2f S = {0.0f, 0.0f};
    float sum = 0.0f;
    float mx  = -1e30f;

    const float* xb = x + b * SEQ;
    float*        tw  = &tile[wid][dd * 1152 + c];           // col c, row j
    const float4* tr4 = (const float4*)&tile[wid][dd * 1152 + c * 36]; // row c

    for (int t0 = 0; t0 < SEQ; t0 += 64) {
        const float xv = xb[t0 + lane];   // 64 timesteps, coalesced

        #pragma unroll
        for (int ch = 0; ch < 2; ++ch) {
            const int j0 = ch * 32;
            // ---- t-phase: 32 steps, 2 pk_fma each, partial -> LDS row ----
            #pragma unroll
            for (int j = 0; j < 32; ++j) {
                const float xt = __int_as_float(
                    __builtin_amdgcn_readlane(__float_as_int(xv), j0 + j));
                const v2f X = {xt, xt};
                S = pk_fma(A2, S, pk_fma(P2, X, Q2));
                tw[j * 36] = S.x + S.y;
            }
            LDS_FENCE();                  // write -> read (wave-private)
            // ---- reduce phase: lane sums its row (t = t0+j0+c) ----
            const float4 q0 = tr4[0], q1 = tr4[1], q2 = tr4[2], q3 = tr4[3];
            const float4 q4 = tr4[4], q5 = tr4[5], q6 = tr4[6], q7 = tr4[7];
            const float4 ssv = ((q0 + q1) + (q2 + q3)) + ((q4 + q5) + (q6 + q7));
            const float xtr = xb[t0 + j0 + c];   // L1 hit
            const float yt  = ((ssv.x + ssv.y) + (ssv.z + ssv.w))
                            + fmaf(xtr, Dw, Db);
            // gelu (tanh approx == x * sigmoid(1.59577x + 0.0713548x^3))
            const float y2 = yt * yt;
            const float zn = yt * fmaf(-0.07135481627f, y2, -1.5957691216f);
            const float h  = yt / (1.0f + __expf(zn));
            sum += h;
            mx = fmaxf(mx, h);
            LDS_FENCE();                  // read -> next write
        }
    }

    // combine within each 32-lane half (offsets <32 never cross halves)
    #pragma unroll
    for (int off = 16; off > 0; off >>= 1) {
        sum += __shfl_xor(sum, off, 64);
        mx   = fmaxf(mx, __shfl_xor(mx, off, 64));
    }
    if (c == 0) {
        pooled[b * (2 * DMODEL) + d]          = sum * (1.0f / SEQ);
        pooled[b * (2 * DMODEL) + DMODEL + d] = mx;
    }
}

// out[b,c] = pooled[b,:] @ W_head[:,c] + b_head[c]   (tiny: 32x512x5)
__global__ __launch_bounds__(256) void head_kernel(
    const float* __restrict__ pooled,
    const float* __restrict__ W_head,
    const float* __restrict__ b_head,
    float* __restrict__ out)
{
    const int tid = blockIdx.x * blockDim.x + threadIdx.x;
    if (tid >= BATCH * NCLS) return;
    const int b = tid / NCLS;
    const int c = tid % NCLS;
    float acc = b_head[c];
    const float* p = pooled + b * (2 * DMODEL);
    for (int k = 0; k < 2 * DMODEL; ++k)
        acc = fmaf(p[k], W_head[k * NCLS + c], acc);
    out[tid] = acc;
}

extern "C" void kernel_launch(void* const* d_in, const int* in_sizes, int n_in,
                              void* d_out, int out_size, void* d_ws, size_t ws_size,
                              hipStream_t stream) {
    const float* x      = (const float*)d_in[0];
    const float* w_in   = (const float*)d_in[1];
    const float* b_in   = (const float*)d_in[2];
    const float* A_diag = (const float*)d_in[3];
    const float* B_in   = (const float*)d_in[4];
    const float* C_out  = (const float*)d_in[5];
    const float* D_skip = (const float*)d_in[6];
    const float* W_head = (const float*)d_in[7];
    const float* b_head = (const float*)d_in[8];
    float* pooled = (float*)d_ws;   // 32*512*4 = 64 KB scratch
    float* out    = (float*)d_out;

    // 4096 waves (2 channels each) = 1024 blocks; 4 blocks/CU, single pass
    ssm_scan_kernel<<<1024, 256, 0, stream>>>(x, w_in, b_in, A_diag, B_in,
                                              C_out, D_skip, pooled);
    head_kernel<<<1, 256, 0, stream>>>(pooled, W_head, b_head, out);
}

// Round 5
// 118.620 us; speedup vs baseline: 2.9031x; 2.9031x over previous
//
#include <hip/hip_runtime.h>

#define BATCH 32
#define SEQ 4096
#define DMODEL 256
#define NCLS 5

typedef short          s8v __attribute__((ext_vector_type(8)));  // 8 bf16 (A/B frag)
typedef unsigned short u8v __attribute__((ext_vector_type(8)));
typedef float          f4v __attribute__((ext_vector_type(4)));  // C/D frag

__device__ __forceinline__ unsigned short f2b(float f) {  // RNE fp32->bf16
    unsigned u = __float_as_uint(f);
    u += 0x7FFFu + ((u >> 16) & 1u);
    return (unsigned short)(u >> 16);
}
__device__ __forceinline__ float b2f(unsigned short u) {
    return __uint_as_float(((unsigned)u) << 16);
}

// One block per channel d. Chunk size 64; group = 4 chunks = 128 cols
// (col = c_local*32 + b). Per group:
//   A: stage x[b, t] tile -> LDS bf16 Xb[col][j]
//   B: XA[n,col] = MA[n,j] * Xb[j,col]           (MFMA, MA[n][j]=A_n^{63-j})
//   C: fp32 scan over 4 chunks: Sig[col][n]=bf16(sigma);
//      sigma = A^64*sigma + P*XA + Q*SA           (exact state propagation)
//   D: y[k,col] = CAT[k,n]*Sig[n,col] + TG[k,j]*Xb[j,col] + Hcp[k] + Dw*x
//      -> gelu -> avg/max pool accumulate (fused epilogue, y never hits HBM)
// MFMA 16x16x32 bf16 layouts (verified m89/m91): A[m=lane&15][k=quad*8+j],
// B[k=quad*8+j][n=lane&15], D: col=lane&15, row=quad*4+reg.
__global__ __launch_bounds__(512) void ssm_mfma_kernel(
    const float* __restrict__ x,      // [B, T]
    const float* __restrict__ w_in,   // [D]
    const float* __restrict__ b_in,   // [D]
    const float* __restrict__ A_diag, // [D, 64]
    const float* __restrict__ B_in,   // [D, 64]
    const float* __restrict__ C_out,  // [D, 64]
    const float* __restrict__ D_skip, // [D]
    float* __restrict__ pooled)       // [B, 2D]
{
    // rows padded to 72 (16B-aligned, banks rotate by 4/row: <=2-way on frags)
    __shared__ unsigned short MAb [64 * 72];
    __shared__ unsigned short CATb[64 * 72];
    __shared__ unsigned short TGb [64 * 72];
    __shared__ unsigned short Xb  [128 * 72];
    __shared__ unsigned short Sigb[128 * 72];
    __shared__ float XAf[128 * 65];   // setup phase: aliased as Pow[65][64]
    __shared__ float Pf[64], Qf[64], Gf[64], Hf[64], Hcp[64];
    __shared__ float ps[8 * 32], pm[8 * 32];

    const int tid  = threadIdx.x;
    const int lane = tid & 63;
    const int wid  = tid >> 6;
    const int m16  = lane & 15;
    const int q4   = (lane >> 4) * 4;
    const int q8   = (lane >> 4) * 8;
    const int cb   = wid * 16;        // this wave's 16-col slice
    const int d    = blockIdx.x;

    // ---- per-thread constants (n = lane) ----
    const int   n  = lane;
    const float An = A_diag[d * 64 + n];
    const float CB = B_in[d * 64 + n] * C_out[d * 64 + n];
    const float wd = w_in[d], bd = b_in[d];
    const float Pn = CB * wd;
    const float Qn = CB * bd;
    const float Dw = D_skip[d] * wd;
    const float Db = D_skip[d] * bd;

    // ---- setup 1: P/Q vectors + power table Pow[m][n]=A_n^m (m=0..64) ----
    if (tid < 64) {
        Pf[n] = Pn; Qf[n] = Qn;
        float p = 1.0f;
        for (int m = 0; m <= 64; ++m) { XAf[m * 64 + n] = p; p *= An; }
    }
    __syncthreads();
    const float A64 = XAf[64 * 64 + n];
    const float cQ  = Qn * (1.0f - A64) / (1.0f - An);   // Q * sum_{m<64} A^m

    // ---- setup 2: MA, CAT (bf16) + G/H vectors ----
    {
        const int r0 = tid >> 3, c0 = (tid & 7) * 8;
        #pragma unroll
        for (int jj = 0; jj < 8; ++jj) {
            const int j = c0 + jj;
            MAb [r0 * 72 + j] = f2b(XAf[(63 - j) * 64 + r0]); // MA[n=r0][j]
            CATb[r0 * 72 + j] = f2b(XAf[(r0 + 1) * 64 + j]);  // CAT[k=r0][n=j]
        }
        if (tid < 64) {
            float g = 0.0f, h = 0.0f;
            for (int nn = 0; nn < 64; ++nn) {
                const float pw = XAf[tid * 64 + nn];
                g = fmaf(pw, Pf[nn], g);
                h = fmaf(pw, Qf[nn], h);
            }
            Gf[tid] = g; Hf[tid] = h;
        }
    }
    __syncthreads();
    // ---- setup 3: Toeplitz TG + prefix-const Hcp ----
    {
        const int k0 = tid >> 3, c0 = (tid & 7) * 8;
        #pragma unroll
        for (int jj = 0; jj < 8; ++jj) {
            const int j = c0 + jj;
            TGb[k0 * 72 + j] = (j <= k0) ? f2b(Gf[k0 - j]) : (unsigned short)0;
        }
        if (tid < 64) {
            float a = Db;
            for (int m = 0; m <= tid; ++m) a += Hf[m];
            Hcp[tid] = a;
        }
    }
    __syncthreads();

    // ---- preload group-invariant A-fragments into registers ----
    s8v aMA[4][2], aCAT[4][2], aTG[4][2];
    #pragma unroll
    for (int rt = 0; rt < 4; ++rt)
        #pragma unroll
        for (int kb = 0; kb < 2; ++kb) {
            const int off = (rt * 16 + m16) * 72 + kb * 32 + q8;
            aMA [rt][kb] = *(const s8v*)&MAb [off];
            aCAT[rt][kb] = *(const s8v*)&CATb[off];
            aTG [rt][kb] = *(const s8v*)&TGb [off];
        }

    // phase-A addressing: thread -> (col, 16-t segment)
    const int colA = tid >> 2;                 // 0..127
    const int j0A  = (tid & 3) * 16;
    const float* xrow = x + (colA & 31) * SEQ + (colA >> 5) * 64 + j0A;
    unsigned short* xdst = &Xb[colA * 72 + j0A];

    float sig[4] = {0.0f, 0.0f, 0.0f, 0.0f};   // state for (n, b=wid*4+i)
    float psum = 0.0f, pmax = -1e30f;

    for (int g = 0; g < 16; ++g) {
        // ---- A: stage x tile (128 cols x 64 j) as bf16 ----
        const float4* xg = (const float4*)(xrow + g * 256);
        const float4 u0 = xg[0], u1 = xg[1], u2 = xg[2], u3 = xg[3];
        u8v lo, hi;
        lo[0]=f2b(u0.x); lo[1]=f2b(u0.y); lo[2]=f2b(u0.z); lo[3]=f2b(u0.w);
        lo[4]=f2b(u1.x); lo[5]=f2b(u1.y); lo[6]=f2b(u1.z); lo[7]=f2b(u1.w);
        hi[0]=f2b(u2.x); hi[1]=f2b(u2.y); hi[2]=f2b(u2.z); hi[3]=f2b(u2.w);
        hi[4]=f2b(u3.x); hi[5]=f2b(u3.y); hi[6]=f2b(u3.z); hi[7]=f2b(u3.w);
        *(u8v*)(xdst)     = lo;
        *(u8v*)(xdst + 8) = hi;
        __syncthreads();

        // ---- B: XA = MA x Xb  (per wave: 4 row-tiles x its 16 cols) ----
        const s8v bx0 = *(const s8v*)&Xb[(cb + m16) * 72 + q8];
        const s8v bx1 = *(const s8v*)&Xb[(cb + m16) * 72 + 32 + q8];
        #pragma unroll
        for (int rt = 0; rt < 4; ++rt) {
            f4v acc = {0.0f, 0.0f, 0.0f, 0.0f};
            acc = __builtin_amdgcn_mfma_f32_16x16x32_bf16(aMA[rt][0], bx0, acc, 0, 0, 0);
            acc = __builtin_amdgcn_mfma_f32_16x16x32_bf16(aMA[rt][1], bx1, acc, 0, 0, 0);
            #pragma unroll
            for (int r = 0; r < 4; ++r)
                XAf[(cb + m16) * 65 + rt * 16 + q4 + r] = acc[r];
        }
        __syncthreads();

        // ---- C: exact fp32 scan, 4 chunks; snapshot sigma -> Sig (bf16) ----
        #pragma unroll
        for (int c = 0; c < 4; ++c) {
            #pragma unroll
            for (int i = 0; i < 4; ++i) {
                const int col = c * 32 + wid * 4 + i;
                Sigb[col * 72 + n] = f2b(sig[i]);
                sig[i] = fmaf(A64, sig[i], fmaf(Pn, XAf[col * 65 + n], cQ));
            }
        }
        __syncthreads();

        // ---- D: y = CAT x Sig + TG x Xb + Hcp + Dw*x -> gelu -> pool ----
        const s8v bs0 = *(const s8v*)&Sigb[(cb + m16) * 72 + q8];
        const s8v bs1 = *(const s8v*)&Sigb[(cb + m16) * 72 + 32 + q8];
        #pragma unroll
        for (int rt = 0; rt < 4; ++rt) {
            f4v acc = {0.0f, 0.0f, 0.0f, 0.0f};
            acc = __builtin_amdgcn_mfma_f32_16x16x32_bf16(aCAT[rt][0], bs0, acc, 0, 0, 0);
            acc = __builtin_amdgcn_mfma_f32_16x16x32_bf16(aCAT[rt][1], bs1, acc, 0, 0, 0);
            acc = __builtin_amdgcn_mfma_f32_16x16x32_bf16(aTG [rt][0], bx0, acc, 0, 0, 0);
            acc = __builtin_amdgcn_mfma_f32_16x16x32_bf16(aTG [rt][1], bx1, acc, 0, 0, 0);
            #pragma unroll
            for (int r = 0; r < 4; ++r) {
                const int k  = rt * 16 + q4 + r;                    // time in chunk
                const float xv = b2f(Xb[(cb + m16) * 72 + k]);
                const float yt = acc[r] + Hcp[k] + Dw * xv;
                const float y2 = yt * yt;
                const float zn = yt * fmaf(-0.07135481627f, y2, -1.5957691216f);
                const float h  = yt * __builtin_amdgcn_rcpf(1.0f + __expf(zn));
                psum += h;
                pmax = fmaxf(pmax, h);
            }
        }
        __syncthreads();
    }

    // ---- pool finalize: combine quads (same b), then waves via LDS ----
    psum += __shfl_xor(psum, 16, 64); psum += __shfl_xor(psum, 32, 64);
    pmax = fmaxf(pmax, __shfl_xor(pmax, 16, 64));
    pmax = fmaxf(pmax, __shfl_xor(pmax, 32, 64));
    if (lane < 16) {            // this wave's b = (wid&1)*16 + m16
        ps[wid * 32 + (wid & 1) * 16 + lane] = psum;
        pm[wid * 32 + (wid & 1) * 16 + lane] = pmax;
    } else if (lane < 32) {     // zero the half this wave doesn't cover
        const int ob = (((wid & 1) ^ 1) * 16) + (lane & 15);
        ps[wid * 32 + ob] = 0.0f;
        pm[wid * 32 + ob] = -1e30f;
    }
    __syncthreads();
    if (tid < 32) {             // tid = b
        float s = 0.0f, m = -1e30f;
        #pragma unroll
        for (int w = 0; w < 8; ++w) {
            s += ps[w * 32 + tid];
            m = fmaxf(m, pm[w * 32 + tid]);
        }
        pooled[tid * (2 * DMODEL) + d]          = s * (1.0f / SEQ);
        pooled[tid * (2 * DMODEL) + DMODEL + d] = m;
    }
}

// out[b,c] = pooled[b,:] @ W_head[:,c] + b_head[c]; one wave per batch row
__global__ __launch_bounds__(64) void head_kernel(
    const float* __restrict__ pooled,
    const float* __restrict__ W_head,
    const float* __restrict__ b_head,
    float* __restrict__ out)
{
    const int b = blockIdx.x, l = threadIdx.x;
    const float* p = pooled + b * (2 * DMODEL);
    float acc[NCLS] = {0, 0, 0, 0, 0};
    for (int k = l; k < 2 * DMODEL; k += 64) {
        const float pv = p[k];
        #pragma unroll
        for (int c = 0; c < NCLS; ++c)
            acc[c] = fmaf(pv, W_head[k * NCLS + c], acc[c]);
    }
    #pragma unroll
    for (int off = 32; off; off >>= 1)
        #pragma unroll
        for (int c = 0; c < NCLS; ++c) acc[c] += __shfl_xor(acc[c], off, 64);
    if (l == 0)
        #pragma unroll
        for (int c = 0; c < NCLS; ++c) out[b * NCLS + c] = acc[c] + b_head[c];
}

extern "C" void kernel_launch(void* const* d_in, const int* in_sizes, int n_in,
                              void* d_out, int out_size, void* d_ws, size_t ws_size,
                              hipStream_t stream) {
    const float* x      = (const float*)d_in[0];
    const float* w_in   = (const float*)d_in[1];
    const float* b_in   = (const float*)d_in[2];
    const float* A_diag = (const float*)d_in[3];
    const float* B_in   = (const float*)d_in[4];
    const float* C_out  = (const float*)d_in[5];
    const float* D_skip = (const float*)d_in[6];
    const float* W_head = (const float*)d_in[7];
    const float* b_head = (const float*)d_in[8];
    float* pooled = (float*)d_ws;   // 32*512*4 = 64 KB scratch
    float* out    = (float*)d_out;

    // one block per channel d; 256 blocks = 1/CU; 512 threads = 8 waves
    ssm_mfma_kernel<<<DMODEL, 512, 0, stream>>>(x, w_in, b_in, A_diag, B_in,
                                                C_out, D_skip, pooled);
    head_kernel<<<BATCH, 64, 0, stream>>>(pooled, W_head, b_head, out);
}